// Round 4
// baseline (119.932 us; speedup 1.0000x reference)
//
#include <hip/hip_runtime.h>
#include <math.h>

#define LN_EPS 1e-5f
#define NM 64
#define E_DIM 128
#define NH 4
#define TOTAL 537600               // 64 * 8400
#define SCALE 0.17677669529663687f // 1/sqrt(32)
#define LOG2E 1.4426950408889634f
#define NPTS 2048
#define XMIN -8.0f
#define XRANGE 16.0f
#define H_STEP (XRANGE / (NPTS - 1))
#define INV_H ((float)(NPTS - 1) / XRANGE)

// ws layout (floats):
//   [0..255]     pool_part[m*4+s]   (64 modes x 4 splits, raw sums)
//   [256..2303]  Ftab[NPTS]         (univariate refined-function table)

// ---------------- pool: 256 blocks (4 per mode) x 256 threads ----------------
__global__ __launch_bounds__(256) void pool_kernel(const float* __restrict__ protos,
                                                   float* __restrict__ pool_part) {
    int bx = blockIdx.x;
    int m = bx >> 2, s = bx & 3;
    const float4* p4 = reinterpret_cast<const float4*>(protos + (size_t)m * 25600);
    float acc = 0.f;
    for (int i = s * 1600 + threadIdx.x; i < (s + 1) * 1600; i += 256) {
        float4 v = p4[i];
        acc += (v.x + v.y) + (v.z + v.w);
    }
#pragma unroll
    for (int off = 32; off; off >>= 1) acc += __shfl_down(acc, off);
    __shared__ float w[4];
    if ((threadIdx.x & 63) == 0) w[threadIdx.x >> 6] = acc;
    __syncthreads();
    if (threadIdx.x == 0) pool_part[bx] = (w[0] + w[1]) + (w[2] + w[3]);
}

// wave-wide xor-butterfly sum: every lane gets the 64-lane total (no LDS, no barrier)
__device__ inline float wave_sum(float v) {
#pragma unroll
    for (int off = 32; off; off >>= 1) v += __shfl_xor(v, off);
    return v;
}

// ---------------- build: 8 blocks x 256 threads, thread t = (m = t>>2, h = t&3) ----
// Builds the (m,h) score/value table in LDS, then evaluates 256 grid points of
// the univariate function F(x) = refined(coeff=x). Single __syncthreads total.
__global__ __launch_bounds__(256) void build_kernel(
    const float* __restrict__ pool_part,
    const float* __restrict__ q_w, const float* __restrict__ q_b,
    const float* __restrict__ q_g, const float* __restrict__ q_beta,
    const float* __restrict__ k_w, const float* __restrict__ k_b,
    const float* __restrict__ k_g, const float* __restrict__ k_beta,
    const float* __restrict__ v_w, const float* __restrict__ v_b,
    const float* __restrict__ v_g, const float* __restrict__ v_beta,
    const float* __restrict__ out_w, const float* __restrict__ out_b,
    float* __restrict__ Ftab) {
    __shared__ float4 tabs[256];
    int t = threadIdx.x;
    int m = t >> 2, h = t & 3;
    int lane = t & 63;

    // ---- q LayerNorm stats: redundant per wave, shuffle-only ----
    float w0 = q_w[lane], w1 = q_w[lane + 64];
    float b0 = q_b[lane], b1 = q_b[lane + 64];
    float mw = wave_sum(w0 + w1) * (1.0f / E_DIM);
    float mb = wave_sum(b0 + b1) * (1.0f / E_DIM);
    float dw0 = w0 - mw, dw1 = w1 - mw, db0 = b0 - mb, db1 = b1 - mb;
    float a2 = wave_sum(fmaf(dw0, dw0, dw1 * dw1)) * (1.0f / E_DIM);
    float a1 = wave_sum(fmaf(dw0, db0, dw1 * db1)) * (1.0f / E_DIM);
    float a0 = wave_sum(fmaf(db0, db0, db1 * db1)) * (1.0f / E_DIM);

    // ---- pooled[m]: 4 raw partials per mode in lanes m*4+{0..3} ----
    float p = pool_part[t];
    p += __shfl_xor(p, 1);
    p += __shfl_xor(p, 2);
    p *= (1.0f / 25600.0f);

    // ---- key/value LN stats for mode m (4 lanes/mode, 32 e's each) ----
    float kin[32], vin[32];
    float sk = 0.f, sv = 0.f;
#pragma unroll
    for (int j = 0; j < 32; ++j) {
        int e = h * 32 + j;
        kin[j] = fmaf(p, k_w[e], k_b[e]);
        vin[j] = fmaf(p, v_w[e], v_b[e]);
        sk += kin[j];
        sv += vin[j];
    }
    sk += __shfl_xor(sk, 1); sk += __shfl_xor(sk, 2);
    sv += __shfl_xor(sv, 1); sv += __shfl_xor(sv, 2);
    float muk = sk * (1.0f / E_DIM), muv = sv * (1.0f / E_DIM);
    float vk = 0.f, vv = 0.f;
#pragma unroll
    for (int j = 0; j < 32; ++j) {
        float dk = kin[j] - muk, dv = vin[j] - muv;
        vk = fmaf(dk, dk, vk);
        vv = fmaf(dv, dv, vv);
    }
    vk += __shfl_xor(vk, 1); vk += __shfl_xor(vk, 2);
    vv += __shfl_xor(vv, 1); vv += __shfl_xor(vv, 2);
    float rk = rsqrtf(vk * (1.0f / E_DIM) + LN_EPS);
    float rv = rsqrtf(vv * (1.0f / E_DIM) + LN_EPS);

    // ---- per (m,h) score/value table entries ----
    float kc = 0.f, k1 = 0.f, kb = 0.f, vwv = 0.f;
#pragma unroll
    for (int j = 0; j < 32; ++j) {
        int e = h * 32 + j;
        float key = fmaf((kin[j] - muk) * rk, k_g[e], k_beta[e]);
        float val = fmaf((vin[j] - muv) * rv, v_g[e], v_beta[e]);
        kc = fmaf((q_w[e] - mw) * q_g[e], key, kc);
        k1 = fmaf((q_b[e] - mb) * q_g[e], key, k1);
        kb = fmaf(q_beta[e], key, kb);
        vwv = fmaf(val, out_w[e], vwv);
    }
    const float SL = SCALE * LOG2E;
    tabs[h * 64 + m] = make_float4(SL * kc, SL * k1, SL * kb, vwv);
    __syncthreads();

    // ---- evaluate F at one grid point per thread ----
    int jpt = blockIdx.x * 256 + t;
    float x = fmaf((float)jpt, H_STEP, XMIN);
    float var = fmaf(x, fmaf(x, a2, 2.0f * a1), a0);
    float r = rsqrtf(var + LN_EPS);
    float al = r * x, be = r;
    float Fv = out_b[0];
#pragma unroll
    for (int hh = 0; hh < NH; ++hh) {
        const float4* th = tabs + hh * 64;
        float den = 0.f, num = 0.f;
#pragma unroll 8
        for (int mm = 0; mm < NM; ++mm) {
            float4 tv = th[mm];
            float s = fmaf(al, tv.x, fmaf(be, tv.y, tv.z));
            float e = exp2f(s);
            den += e;
            num = fmaf(e, tv.w, num);
        }
        Fv += num / den;
    }
    Ftab[jpt] = Fv;
}

// ---------------- apply: elementwise lerp + gate, 4 elems/thread ----------------
__global__ __launch_bounds__(256) void apply_kernel(
    const float4* __restrict__ coeff4,
    const float* __restrict__ Ftab_g,
    const float* __restrict__ gate_w,
    const float* __restrict__ gate_b,
    float4* __restrict__ out4) {
    __shared__ float Ft[NPTS];
    {
        const float4* F4 = (const float4*)Ftab_g;
        float4* Fs4 = (float4*)Ft;
#pragma unroll
        for (int k = 0; k < NPTS / 4 / 256; ++k)
            Fs4[threadIdx.x + k * 256] = F4[threadIdx.x + k * 256];
    }
    __syncthreads();

    int idx = blockIdx.x * 256 + threadIdx.x;  // 525*256 float4 = 537600 elems
    float4 c4 = coeff4[idx];
    float c[4] = {c4.x, c4.y, c4.z, c4.w};
    float gw0 = gate_w[0], gw1 = gate_w[1], gb = gate_b[0];
    float o[4];
#pragma unroll
    for (int i = 0; i < 4; ++i) {
        float u = (c[i] - XMIN) * INV_H;
        u = fminf(fmaxf(u, 0.0f), (float)(NPTS - 2));  // F flat at edges
        float jf = floorf(u);
        int j = (int)jf;
        float f = u - jf;
        float F0 = Ft[j], F1 = Ft[j + 1];
        float Fv = fmaf(f, F1 - F0, F0);
        float z = fmaf(c[i], gw0, fmaf(Fv, gw1, gb));
        float g = 1.0f / (1.0f + __expf(-z));
        o[i] = fmaf(g, Fv - c[i], c[i]);  // g*refined + (1-g)*c
    }
    out4[idx] = make_float4(o[0], o[1], o[2], o[3]);
}

extern "C" void kernel_launch(void* const* d_in, const int* in_sizes, int n_in,
                              void* d_out, int out_size, void* d_ws, size_t ws_size,
                              hipStream_t stream) {
    const float* coeff   = (const float*)d_in[0];
    const float* protos  = (const float*)d_in[1];
    const float* q_w     = (const float*)d_in[2];
    const float* q_b     = (const float*)d_in[3];
    const float* q_g     = (const float*)d_in[4];
    const float* q_beta  = (const float*)d_in[5];
    const float* k_w     = (const float*)d_in[6];
    const float* k_b     = (const float*)d_in[7];
    const float* k_g     = (const float*)d_in[8];
    const float* k_beta  = (const float*)d_in[9];
    const float* v_w     = (const float*)d_in[10];
    const float* v_b     = (const float*)d_in[11];
    const float* v_g     = (const float*)d_in[12];
    const float* v_beta  = (const float*)d_in[13];
    const float* out_w   = (const float*)d_in[14];
    const float* out_b   = (const float*)d_in[15];
    const float* gate_w  = (const float*)d_in[16];
    const float* gate_b  = (const float*)d_in[17];

    float* ws        = (float*)d_ws;
    float* pool_part = ws;          // 256 floats
    float* Ftab      = ws + 256;    // NPTS floats (1 KiB offset -> 16B aligned)

    pool_kernel<<<256, 256, 0, stream>>>(protos, pool_part);
    build_kernel<<<NPTS / 256, 256, 0, stream>>>(pool_part,
        q_w, q_b, q_g, q_beta, k_w, k_b, k_g, k_beta,
        v_w, v_b, v_g, v_beta, out_w, out_b, Ftab);
    apply_kernel<<<TOTAL / 4 / 256, 256, 0, stream>>>(
        (const float4*)coeff, Ftab, gate_w, gate_b, (float4*)d_out);
}